// Round 6
// baseline (357.089 us; speedup 1.0000x reference)
//
#include <hip/hip_runtime.h>
#include <math.h>

#define VOCAB 32000
#define E_DIM 512
#define H_DIM 1024
#define S_LEN 50
#define B_SZ 64
#define T_LEN 10
#define H3 (3 * H_DIM)
#define D2H (2 * H_DIM)

typedef __attribute__((ext_vector_type(8))) short short8;
typedef __attribute__((ext_vector_type(4))) float floatx4;

__device__ __forceinline__ ushort f2b(float f) {
    union { float f; uint32_t u; } x; x.f = f;
    uint32_t r = (x.u + 0x7fff + ((x.u >> 16) & 1)) >> 16;  // RNE
    return (ushort)r;
}
__device__ __forceinline__ float b2f(ushort u) {
    union { float f; uint32_t u; } x; x.u = ((uint32_t)u) << 16;
    return x.f;
}
__device__ __forceinline__ float fast_sigmoid(float x) {
    x = fminf(fmaxf(x, -30.f), 30.f);
    return 1.f / (1.f + __expf(-x));
}
__device__ __forceinline__ float fast_tanh(float x) {
    x = fminf(fmaxf(x, -15.f), 15.f);
    float e = __expf(2.f * x);
    return (e - 1.f) / (e + 1.f);
}

// ---------------------------------------------------------------------------
// Fused prep: 4 weight converts + keys gather + embed gather + h0 + barrier init
// ---------------------------------------------------------------------------
#define PB0 1536
#define PB1 (PB0 + 3072)
#define PB2 (PB1 + 2048)
#define PB3 (PB2 + 1024)
#define PB4 (PB3 + 3200)
#define PB5 (PB4 + 640)
#define PB6 (PB5 + 64)

__device__ __forceinline__ void cvt_chunk(const float* src, ushort* dst, int i) {
    float4 v = ((const float4*)src)[i];
    ushort4 o;
    o.x = f2b(v.x); o.y = f2b(v.y); o.z = f2b(v.z); o.w = f2b(v.w);
    ((ushort4*)dst)[i] = o;
}

__global__ __launch_bounds__(256) void prep(
    const float* __restrict__ w_ih, ushort* __restrict__ w_ihb,
    const float* __restrict__ w_hh, ushort* __restrict__ w_hhb,
    const float* __restrict__ ua_w, ushort* __restrict__ ua_wb,
    const float* __restrict__ wa_w, ushort* __restrict__ wa_wb,
    const float* __restrict__ enc_out, ushort* __restrict__ keysb,
    const int* __restrict__ target, const float* __restrict__ emb,
    ushort* __restrict__ Xb,
    const float* __restrict__ hidden, ushort* __restrict__ hb0,
    int* __restrict__ bar) {
    int bid = blockIdx.x, tid = threadIdx.x;
    if (bid == 0) {
        for (int i = tid; i < 4096; i += 256) bar[i] = 0;
    }
    if (bid < PB0) {
        cvt_chunk(w_ih, w_ihb, bid * 256 + tid);
    } else if (bid < PB1) {
        cvt_chunk(w_hh, w_hhb, (bid - PB0) * 256 + tid);
    } else if (bid < PB2) {
        cvt_chunk(ua_w, ua_wb, (bid - PB1) * 256 + tid);
    } else if (bid < PB3) {
        cvt_chunk(wa_w, wa_wb, (bid - PB2) * 256 + tid);
    } else if (bid < PB4) {
        int bs = bid - PB3;                   // b*S + s
        int b = bs / S_LEN, s = bs % S_LEN;
        const float* src = enc_out + ((size_t)s * B_SZ + b) * D2H;
        ushort* dst = keysb + (size_t)bs * D2H;
#pragma unroll
        for (int p = 0; p < 2; ++p) {
            int i = tid + p * 256;
            float4 v = ((const float4*)src)[i];
            ushort4 o;
            o.x = f2b(v.x); o.y = f2b(v.y); o.z = f2b(v.z); o.w = f2b(v.w);
            ((ushort4*)dst)[i] = o;
        }
    } else if (bid < PB5) {
        int m = bid - PB4;                    // t*B + b
        int t = m / B_SZ, b = m % B_SZ;
        int idx = (t == 0) ? 0 : target[b * T_LEN + (t - 1)];
        if (tid < 128) {
            const float* src = emb + (size_t)idx * E_DIM;
            float4 v = ((const float4*)src)[tid];
            ushort4 o;
            o.x = f2b(v.x); o.y = f2b(v.y); o.z = f2b(v.z); o.w = f2b(v.w);
            ((ushort4*)(Xb + (size_t)m * E_DIM))[tid] = o;
        }
    } else {
        cvt_chunk(hidden, hb0, (bid - PB5) * 256 + tid);
    }
}

// ---------------------------------------------------------------------------
// bf16 MFMA GEMM: C = A[M,K] @ W[N,K]^T + bias. BM=64, BN=128, BK=64.
// Two GEMMs merged per dispatch via GemmArgs pair (bid switch).
// ---------------------------------------------------------------------------
struct GemmArgs {
    const ushort* A; const ushort* W; const float* bias;
    float* Cf; ushort* C16;
    int M, N, K, nbn, nblk;
};

__global__ __launch_bounds__(256) void gemm_bf16(GemmArgs g0, GemmArgs g1) {
    const bool first = (int)blockIdx.x < g0.nblk;
    GemmArgs g = first ? g0 : g1;
    const int bid = first ? blockIdx.x : (blockIdx.x - g0.nblk);

    __shared__ ushort As[64 * 72];
    __shared__ ushort Bs[128 * 72];

    const int tid = threadIdx.x;
    const int w = tid >> 6, lane = tid & 63;
    const int lm = lane & 15, q = lane >> 4;
    const int wm = w >> 1, wn = w & 1;
    const int n0 = (bid % g.nbn) * 128;
    const int m0 = (bid / g.nbn) * 64;
    const int K = g.K;

    floatx4 acc[2][4];
#pragma unroll
    for (int i = 0; i < 2; ++i)
#pragma unroll
        for (int j = 0; j < 4; ++j)
            acc[i][j] = (floatx4){0.f, 0.f, 0.f, 0.f};

    short8 ar[2], br[4];
    auto load_tiles = [&](int k0) {
#pragma unroll
        for (int p = 0; p < 2; ++p) {
            int c = tid + p * 256;
            ar[p] = *(const short8*)&g.A[(size_t)(m0 + (c >> 3)) * K + k0 + (c & 7) * 8];
        }
#pragma unroll
        for (int p = 0; p < 4; ++p) {
            int c = tid + p * 256;
            br[p] = *(const short8*)&g.W[(size_t)(n0 + (c >> 3)) * K + k0 + (c & 7) * 8];
        }
    };

    load_tiles(0);
    for (int k0 = 0; k0 < K; k0 += 64) {
#pragma unroll
        for (int p = 0; p < 2; ++p) {
            int c = tid + p * 256;
            *(short8*)&As[(c >> 3) * 72 + (c & 7) * 8] = ar[p];
        }
#pragma unroll
        for (int p = 0; p < 4; ++p) {
            int c = tid + p * 256;
            *(short8*)&Bs[(c >> 3) * 72 + (c & 7) * 8] = br[p];
        }
        __syncthreads();
        if (k0 + 64 < K) load_tiles(k0 + 64);

#pragma unroll
        for (int kk = 0; kk < 2; ++kk) {
            short8 af[2], bf[4];
#pragma unroll
            for (int i = 0; i < 2; ++i)
                af[i] = *(const short8*)&As[(wm * 32 + i * 16 + lm) * 72 + kk * 32 + q * 8];
#pragma unroll
            for (int j = 0; j < 4; ++j)
                bf[j] = *(const short8*)&Bs[(wn * 64 + j * 16 + lm) * 72 + kk * 32 + q * 8];
#pragma unroll
            for (int i = 0; i < 2; ++i)
#pragma unroll
                for (int j = 0; j < 4; ++j)
                    acc[i][j] = __builtin_amdgcn_mfma_f32_16x16x32_bf16(af[i], bf[j], acc[i][j], 0, 0, 0);
        }
        __syncthreads();
    }

    float bv[4];
#pragma unroll
    for (int j = 0; j < 4; ++j)
        bv[j] = g.bias[n0 + wn * 64 + j * 16 + lm];
#pragma unroll
    for (int i = 0; i < 2; ++i) {
#pragma unroll
        for (int j = 0; j < 4; ++j) {
            int col = n0 + wn * 64 + j * 16 + lm;
#pragma unroll
            for (int r = 0; r < 4; ++r) {
                int row = m0 + wm * 32 + i * 16 + q * 4 + r;
                float v = acc[i][j][r] + bv[j];
                if (g.C16) g.C16[(size_t)row * g.N + col] = f2b(v);
                else       g.Cf[(size_t)row * g.N + col] = v;
            }
        }
    }
}

// ---------------------------------------------------------------------------
// Persistent GRU v3: 64 blocks (1/CU), block owns 16 h-columns.
// w_hh slice (48 x 1024 = 97 KB) in LDS once. Per step: ALL 32 h-chunk
// loads issued up-front (deep vmem pipeline, ~200 VGPRs, 1 wave/SIMD so
// budget is fine); GI for step t+1 prefetched BEFORE the barrier so its
// latency overlaps the barrier wait. Barrier: phase-indexed hierarchical
// arrival + load-only polling.
// ---------------------------------------------------------------------------
#define GRU_BLOCKS 64
#define WS_STRIDE 1032   // elements; 2064B row stride -> 2-way max bank alias (free)

__device__ __forceinline__ void grid_barrier(int* __restrict__ bar, int t, int bid) {
    __syncthreads();
    if (threadIdx.x == 0) {
        __threadfence();
        int g = bid & 7;
        int sub = __hip_atomic_fetch_add(&bar[(t * 8 + g) * 32], 1,
                                         __ATOMIC_ACQ_REL, __HIP_MEMORY_SCOPE_AGENT);
        if (sub == 7) {
            int m = __hip_atomic_fetch_add(&bar[2560 + t * 32], 1,
                                           __ATOMIC_ACQ_REL, __HIP_MEMORY_SCOPE_AGENT);
            if (m == 7)
                __hip_atomic_store(&bar[3040], t + 1,
                                   __ATOMIC_RELEASE, __HIP_MEMORY_SCOPE_AGENT);
        }
        while (__hip_atomic_load(&bar[3040], __ATOMIC_ACQUIRE,
                                 __HIP_MEMORY_SCOPE_AGENT) <= t)
            __builtin_amdgcn_s_sleep(1);
        __threadfence();
    }
    __syncthreads();
}

__global__ __launch_bounds__(256, 1) void gru_persistent(
    const ushort* __restrict__ w_hhb, const float* __restrict__ bhh,
    const float* __restrict__ GI, const float* __restrict__ hidden,
    ushort* __restrict__ hb0, ushort* __restrict__ hb1,
    ushort* __restrict__ hsb, float* __restrict__ outTail,
    int* __restrict__ bar) {
    __shared__ ushort Ws[48 * WS_STRIDE];   // persistent across steps
    const int tid = threadIdx.x;
    const int w = tid >> 6, lane = tid & 63;
    const int lm = lane & 15, q = lane >> 4;
    const int bid = blockIdx.x;
    const int j0 = bid * 16;
    const int j = j0 + lm;

    // one-time: stage w_hh slice into LDS
#pragma unroll
    for (int p = 0; p < 24; ++p) {
        int c = tid + p * 256;                // 6144 chunks: row=c>>7, off=c&127
        int row = c >> 7, off = c & 127;
        int grow = (row >> 4) * H_DIM + j0 + (row & 15);
        *(short8*)&Ws[row * WS_STRIDE + off * 8] =
            *(const short8*)&w_hhb[(size_t)grow * H_DIM + off * 8];
    }

    const float bhr = bhh[j], bhz = bhh[H_DIM + j], bhn = bhh[2 * H_DIM + j];

    float hf[4];
#pragma unroll
    for (int r = 0; r < 4; ++r)
        hf[r] = hidden[(size_t)(w * 16 + q * 4 + r) * H_DIM + j];

    // GI prefetch for t=0 (in flight across the staging syncthreads)
    float ir[4], iz[4], inn[4];
#pragma unroll
    for (int r = 0; r < 4; ++r) {
        const float* gi = GI + (size_t)(w * 16 + q * 4 + r) * H3 + j;
        ir[r] = gi[0]; iz[r] = gi[H_DIM]; inn[r] = gi[2 * H_DIM];
    }

    __syncthreads();   // Ws ready

    for (int t = 0; t < T_LEN; ++t) {
        const ushort* hin = (t & 1) ? hb1 : hb0;
        ushort* hout = (t & 1) ? hb0 : hb1;
        const ushort* arow = hin + (size_t)(w * 16 + lm) * H_DIM + q * 8;

        // issue ALL 32 h-chunk loads up front (deep pipeline)
        short8 hreg[32];
#pragma unroll
        for (int c = 0; c < 32; ++c)
            hreg[c] = *(const short8*)&arow[c * 32];

        floatx4 accr = {0.f, 0.f, 0.f, 0.f};
        floatx4 accz = {0.f, 0.f, 0.f, 0.f};
        floatx4 accn = {0.f, 0.f, 0.f, 0.f};

#pragma unroll
        for (int it = 0; it < 8; ++it) {       // K=1024, 128 per iter
#pragma unroll
            for (int kk = 0; kk < 4; ++kk) {
                const short8 af = hreg[it * 4 + kk];
                const int ko = it * 128 + kk * 32 + q * 8;
                short8 b0 = *(const short8*)&Ws[(lm) * WS_STRIDE + ko];
                short8 b1 = *(const short8*)&Ws[(16 + lm) * WS_STRIDE + ko];
                short8 b2 = *(const short8*)&Ws[(32 + lm) * WS_STRIDE + ko];
                accr = __builtin_amdgcn_mfma_f32_16x16x32_bf16(af, b0, accr, 0, 0, 0);
                accz = __builtin_amdgcn_mfma_f32_16x16x32_bf16(af, b1, accz, 0, 0, 0);
                accn = __builtin_amdgcn_mfma_f32_16x16x32_bf16(af, b2, accn, 0, 0, 0);
            }
        }

        // epilogue (ir/iz/inn prefetched before previous barrier)
#pragma unroll
        for (int r = 0; r < 4; ++r) {
            int b = w * 16 + q * 4 + r;
            float rg = fast_sigmoid(ir[r] + accr[r] + bhr);
            float z  = fast_sigmoid(iz[r] + accz[r] + bhz);
            float ng = fast_tanh(inn[r] + rg * (accn[r] + bhn));
            float hnew = (1.f - z) * ng + z * hf[r];
            hf[r] = hnew;
            size_t hi = (size_t)b * H_DIM + j;
            ushort h16 = f2b(hnew);
            hout[hi] = h16;
            hsb[(size_t)t * B_SZ * H_DIM + hi] = h16;
            if (t == T_LEN - 1) outTail[hi] = hnew;
        }

        if (t < T_LEN - 1) {
            // prefetch GI for t+1 -- lands during the barrier wait
#pragma unroll
            for (int r = 0; r < 4; ++r) {
                const float* gi = GI + (size_t)((t + 1) * B_SZ + w * 16 + q * 4 + r) * H3 + j;
                ir[r] = gi[0]; iz[r] = gi[H_DIM]; inn[r] = gi[2 * H_DIM];
            }
            grid_barrier(bar, t, bid);
        }
    }
}

// ---------------------------------------------------------------------------
// Fused attention: scores + softmax + context + log_softmax.
// ---------------------------------------------------------------------------
__global__ __launch_bounds__(256) void attn_ctx(
    const ushort* __restrict__ WQ16, const ushort* __restrict__ UK16,
    const float* __restrict__ va_w, const float* __restrict__ va_b,
    const ushort* __restrict__ keysb, float* __restrict__ out) {
    __shared__ float wq_s[H_DIM];
    __shared__ float va_s[H_DIM];
    __shared__ float sc[S_LEN];
    __shared__ float wred[4];
    __shared__ float sred[4];
    const int bt = blockIdx.x;       // t*64 + b
    const int t = bt >> 6, b = bt & 63;
    const int tid = threadIdx.x;
    const int wave = tid >> 6, lane = tid & 63;

    for (int hh = tid; hh < H_DIM; hh += 256) {
        wq_s[hh] = b2f(WQ16[(size_t)(t * B_SZ + b) * H_DIM + hh]);
        va_s[hh] = va_w[hh];
    }
    __syncthreads();

    for (int s = wave; s < S_LEN; s += 4) {
        const ushort* uk = UK16 + ((size_t)b * S_LEN + s) * H_DIM + lane * 16;
        short8 u0 = *(const short8*)&uk[0];
        short8 u1 = *(const short8*)&uk[8];
        float acc = 0.f;
        const int h0 = lane * 16;
#pragma unroll
        for (int i = 0; i < 8; ++i)
            acc += fast_tanh(wq_s[h0 + i] + b2f((ushort)u0[i])) * va_s[h0 + i];
#pragma unroll
        for (int i = 0; i < 8; ++i)
            acc += fast_tanh(wq_s[h0 + 8 + i] + b2f((ushort)u1[i])) * va_s[h0 + 8 + i];
        for (int off = 32; off > 0; off >>= 1) acc += __shfl_down(acc, off);
        if (lane == 0) sc[s] = acc + va_b[0];
    }
    __syncthreads();

    if (tid < 64) {
        float v = (tid < S_LEN) ? sc[tid] : -INFINITY;
        float m = v;
        for (int off = 32; off > 0; off >>= 1) m = fmaxf(m, __shfl_down(m, off));
        m = __shfl(m, 0);
        float e = (tid < S_LEN) ? __expf(v - m) : 0.f;
        float sum = e;
        for (int off = 32; off > 0; off >>= 1) sum += __shfl_down(sum, off);
        sum = __shfl(sum, 0);
        if (tid < S_LEN) sc[tid] = e / sum;
    }
    __syncthreads();

    float c[8];
#pragma unroll
    for (int i = 0; i < 8; ++i) c[i] = 0.f;
    const ushort* kb = keysb + (size_t)b * S_LEN * D2H + tid * 8;
    for (int s = 0; s < S_LEN; ++s) {
        float ws = sc[s];
        short8 kv = *(const short8*)&kb[(size_t)s * D2H];
#pragma unroll
        for (int i = 0; i < 8; ++i) c[i] += ws * b2f((ushort)kv[i]);
    }

    float m = c[0];
#pragma unroll
    for (int i = 1; i < 8; ++i) m = fmaxf(m, c[i]);
    for (int off = 32; off > 0; off >>= 1) m = fmaxf(m, __shfl_down(m, off));
    if (lane == 0) wred[wave] = m;
    __syncthreads();
    if (tid == 0) wred[0] = fmaxf(fmaxf(wred[0], wred[1]), fmaxf(wred[2], wred[3]));
    __syncthreads();
    m = wred[0];
    float sum = 0.f;
#pragma unroll
    for (int i = 0; i < 8; ++i) sum += __expf(c[i] - m);
    for (int off = 32; off > 0; off >>= 1) sum += __shfl_down(sum, off);
    if (lane == 0) sred[wave] = sum;
    __syncthreads();
    if (tid == 0) sred[0] = sred[0] + sred[1] + sred[2] + sred[3];
    __syncthreads();
    float lse = m + __logf(sred[0]);

    float* o = out + ((size_t)b * T_LEN + t) * D2H + tid * 8;
#pragma unroll
    for (int i = 0; i < 8; ++i) o[i] = c[i] - lse;
}

// ---------------------------------------------------------------------------
extern "C" void kernel_launch(void* const* d_in, const int* in_sizes, int n_in,
                              void* d_out, int out_size, void* d_ws, size_t ws_size,
                              hipStream_t stream) {
    const float* enc_out = (const float*)d_in[0];
    const float* hidden  = (const float*)d_in[1];
    const int*   target  = (const int*)d_in[2];
    const float* emb     = (const float*)d_in[3];
    const float* w_ih    = (const float*)d_in[4];
    const float* w_hh    = (const float*)d_in[5];
    const float* b_ih    = (const float*)d_in[6];
    const float* b_hh    = (const float*)d_in[7];
    const float* wa_w    = (const float*)d_in[8];
    const float* wa_b    = (const float*)d_in[9];
    const float* ua_w    = (const float*)d_in[10];
    const float* ua_b    = (const float*)d_in[11];
    const float* va_w    = (const float*)d_in[12];
    const float* va_b    = (const float*)d_in[13];
    float* out = (float*)d_out;

    const int TB = T_LEN * B_SZ;               // 640
    const int BS = B_SZ * S_LEN;               // 3200

    // workspace carve
    char* p = (char*)d_ws;
    int*    bar   = (int*)p;    p += 4096 * 4;
    float*  GI    = (float*)p;  p += (size_t)TB * H3 * 4;
    p = (char*)(((uintptr_t)p + 255) & ~(uintptr_t)255);
    ushort* keysb = (ushort*)p; p += (size_t)BS * D2H * 2;
    ushort* Xb    = (ushort*)p; p += (size_t)TB * E_DIM * 2;
    ushort* w_ihb = (ushort*)p; p += (size_t)H3 * E_DIM * 2;
    ushort* w_hhb = (ushort*)p; p += (size_t)H3 * H_DIM * 2;
    ushort* ua_wb = (ushort*)p; p += (size_t)H_DIM * D2H * 2;
    ushort* wa_wb = (ushort*)p; p += (size_t)H_DIM * H_DIM * 2;
    ushort* hb0   = (ushort*)p; p += (size_t)B_SZ * H_DIM * 2;
    ushort* hb1   = (ushort*)p; p += (size_t)B_SZ * H_DIM * 2;
    ushort* hsb   = (ushort*)p; p += (size_t)TB * H_DIM * 2;
    ushort* UK16  = (ushort*)p; p += (size_t)BS * H_DIM * 2;
    ushort* WQ16  = (ushort*)p; p += (size_t)TB * H_DIM * 2;

    // prep
    prep<<<PB6, 256, 0, stream>>>(w_ih, w_ihb, w_hh, w_hhb, ua_w, ua_wb, wa_w, wa_wb,
                                  enc_out, keysb, target, emb, Xb, hidden, hb0, bar);

    // merged UK + GI GEMMs
    GemmArgs guk = { keysb, ua_wb, ua_b, nullptr, UK16,
                     BS, H_DIM, D2H, H_DIM / 128, (BS / 64) * (H_DIM / 128) };
    GemmArgs ggi = { Xb, w_ihb, b_ih, GI, nullptr,
                     TB, H3, E_DIM, H3 / 128, (TB / 64) * (H3 / 128) };
    gemm_bf16<<<guk.nblk + ggi.nblk, 256, 0, stream>>>(guk, ggi);

    // persistent GRU (writes hsb + h_last f32 tail)
    float* outTail = out + (size_t)B_SZ * T_LEN * D2H;
    gru_persistent<<<GRU_BLOCKS, 256, 0, stream>>>(w_hhb, b_hh, GI, hidden,
                                                   hb0, hb1, hsb, outTail, bar);

    // WQ = hs @ wa_w^T + wa_b  -> bf16
    GemmArgs gwq = { hsb, wa_wb, wa_b, nullptr, WQ16,
                     TB, H_DIM, H_DIM, H_DIM / 128, (TB / 64) * (H_DIM / 128) };
    gemm_bf16<<<gwq.nblk, 256, 0, stream>>>(gwq, gwq);

    // fused attention + context + log_softmax
    attn_ctx<<<B_SZ * T_LEN, 256, 0, stream>>>(WQ16, UK16, va_w, va_b, keysb, out);
}

// Round 7
// 332.921 us; speedup vs baseline: 1.0726x; 1.0726x over previous
//
#include <hip/hip_runtime.h>
#include <math.h>

#define VOCAB 32000
#define E_DIM 512
#define H_DIM 1024
#define S_LEN 50
#define B_SZ 64
#define T_LEN 10
#define H3 (3 * H_DIM)
#define D2H (2 * H_DIM)

typedef __attribute__((ext_vector_type(8))) short short8;
typedef __attribute__((ext_vector_type(4))) float floatx4;

__device__ __forceinline__ ushort f2b(float f) {
    union { float f; uint32_t u; } x; x.f = f;
    uint32_t r = (x.u + 0x7fff + ((x.u >> 16) & 1)) >> 16;  // RNE
    return (ushort)r;
}
__device__ __forceinline__ float b2f(ushort u) {
    union { float f; uint32_t u; } x; x.u = ((uint32_t)u) << 16;
    return x.f;
}
__device__ __forceinline__ float fast_sigmoid(float x) {
    x = fminf(fmaxf(x, -30.f), 30.f);
    return 1.f / (1.f + __expf(-x));
}
__device__ __forceinline__ float fast_tanh(float x) {
    x = fminf(fmaxf(x, -15.f), 15.f);
    float e = __expf(2.f * x);
    return (e - 1.f) / (e + 1.f);
}

// ---------------------------------------------------------------------------
// Fused prep: 4 weight converts + keys gather + embed gather + h0 + barrier init
// ---------------------------------------------------------------------------
#define PB0 1536
#define PB1 (PB0 + 3072)
#define PB2 (PB1 + 2048)
#define PB3 (PB2 + 1024)
#define PB4 (PB3 + 3200)
#define PB5 (PB4 + 640)
#define PB6 (PB5 + 64)

__device__ __forceinline__ void cvt_chunk(const float* src, ushort* dst, int i) {
    float4 v = ((const float4*)src)[i];
    ushort4 o;
    o.x = f2b(v.x); o.y = f2b(v.y); o.z = f2b(v.z); o.w = f2b(v.w);
    ((ushort4*)dst)[i] = o;
}

__global__ __launch_bounds__(256) void prep(
    const float* __restrict__ w_ih, ushort* __restrict__ w_ihb,
    const float* __restrict__ w_hh, ushort* __restrict__ w_hhb,
    const float* __restrict__ ua_w, ushort* __restrict__ ua_wb,
    const float* __restrict__ wa_w, ushort* __restrict__ wa_wb,
    const float* __restrict__ enc_out, ushort* __restrict__ keysb,
    const int* __restrict__ target, const float* __restrict__ emb,
    ushort* __restrict__ Xb,
    const float* __restrict__ hidden, ushort* __restrict__ hb0,
    int* __restrict__ bar) {
    int bid = blockIdx.x, tid = threadIdx.x;
    if (bid == 0) {
        for (int i = tid; i < 4096; i += 256)
            __hip_atomic_store(&bar[i], 0, __ATOMIC_RELAXED, __HIP_MEMORY_SCOPE_AGENT);
    }
    if (bid < PB0) {
        cvt_chunk(w_ih, w_ihb, bid * 256 + tid);
    } else if (bid < PB1) {
        cvt_chunk(w_hh, w_hhb, (bid - PB0) * 256 + tid);
    } else if (bid < PB2) {
        cvt_chunk(ua_w, ua_wb, (bid - PB1) * 256 + tid);
    } else if (bid < PB3) {
        cvt_chunk(wa_w, wa_wb, (bid - PB2) * 256 + tid);
    } else if (bid < PB4) {
        int bs = bid - PB3;                   // b*S + s
        int b = bs / S_LEN, s = bs % S_LEN;
        const float* src = enc_out + ((size_t)s * B_SZ + b) * D2H;
        ushort* dst = keysb + (size_t)bs * D2H;
#pragma unroll
        for (int p = 0; p < 2; ++p) {
            int i = tid + p * 256;
            float4 v = ((const float4*)src)[i];
            ushort4 o;
            o.x = f2b(v.x); o.y = f2b(v.y); o.z = f2b(v.z); o.w = f2b(v.w);
            ((ushort4*)dst)[i] = o;
        }
    } else if (bid < PB5) {
        int m = bid - PB4;                    // t*B + b
        int t = m / B_SZ, b = m % B_SZ;
        int idx = (t == 0) ? 0 : target[b * T_LEN + (t - 1)];
        if (tid < 128) {
            const float* src = emb + (size_t)idx * E_DIM;
            float4 v = ((const float4*)src)[tid];
            ushort4 o;
            o.x = f2b(v.x); o.y = f2b(v.y); o.z = f2b(v.z); o.w = f2b(v.w);
            ((ushort4*)(Xb + (size_t)m * E_DIM))[tid] = o;
        }
    } else {
        cvt_chunk(hidden, hb0, (bid - PB5) * 256 + tid);
    }
}

// ---------------------------------------------------------------------------
// bf16 MFMA GEMM: C = A[M,K] @ W[N,K]^T + bias. BM=64, BN=128, BK=64.
// Two GEMMs merged per dispatch via GemmArgs pair (bid switch).
// ---------------------------------------------------------------------------
struct GemmArgs {
    const ushort* A; const ushort* W; const float* bias;
    float* Cf; ushort* C16;
    int M, N, K, nbn, nblk;
};

__global__ __launch_bounds__(256) void gemm_bf16(GemmArgs g0, GemmArgs g1) {
    const bool first = (int)blockIdx.x < g0.nblk;
    GemmArgs g = first ? g0 : g1;
    const int bid = first ? blockIdx.x : (blockIdx.x - g0.nblk);

    __shared__ ushort As[64 * 72];
    __shared__ ushort Bs[128 * 72];

    const int tid = threadIdx.x;
    const int w = tid >> 6, lane = tid & 63;
    const int lm = lane & 15, q = lane >> 4;
    const int wm = w >> 1, wn = w & 1;
    const int n0 = (bid % g.nbn) * 128;
    const int m0 = (bid / g.nbn) * 64;
    const int K = g.K;

    floatx4 acc[2][4];
#pragma unroll
    for (int i = 0; i < 2; ++i)
#pragma unroll
        for (int j = 0; j < 4; ++j)
            acc[i][j] = (floatx4){0.f, 0.f, 0.f, 0.f};

    short8 ar[2], br[4];
    auto load_tiles = [&](int k0) {
#pragma unroll
        for (int p = 0; p < 2; ++p) {
            int c = tid + p * 256;
            ar[p] = *(const short8*)&g.A[(size_t)(m0 + (c >> 3)) * K + k0 + (c & 7) * 8];
        }
#pragma unroll
        for (int p = 0; p < 4; ++p) {
            int c = tid + p * 256;
            br[p] = *(const short8*)&g.W[(size_t)(n0 + (c >> 3)) * K + k0 + (c & 7) * 8];
        }
    };

    load_tiles(0);
    for (int k0 = 0; k0 < K; k0 += 64) {
#pragma unroll
        for (int p = 0; p < 2; ++p) {
            int c = tid + p * 256;
            *(short8*)&As[(c >> 3) * 72 + (c & 7) * 8] = ar[p];
        }
#pragma unroll
        for (int p = 0; p < 4; ++p) {
            int c = tid + p * 256;
            *(short8*)&Bs[(c >> 3) * 72 + (c & 7) * 8] = br[p];
        }
        __syncthreads();
        if (k0 + 64 < K) load_tiles(k0 + 64);

#pragma unroll
        for (int kk = 0; kk < 2; ++kk) {
            short8 af[2], bf[4];
#pragma unroll
            for (int i = 0; i < 2; ++i)
                af[i] = *(const short8*)&As[(wm * 32 + i * 16 + lm) * 72 + kk * 32 + q * 8];
#pragma unroll
            for (int j = 0; j < 4; ++j)
                bf[j] = *(const short8*)&Bs[(wn * 64 + j * 16 + lm) * 72 + kk * 32 + q * 8];
#pragma unroll
            for (int i = 0; i < 2; ++i)
#pragma unroll
                for (int j = 0; j < 4; ++j)
                    acc[i][j] = __builtin_amdgcn_mfma_f32_16x16x32_bf16(af[i], bf[j], acc[i][j], 0, 0, 0);
        }
        __syncthreads();
    }

    float bv[4];
#pragma unroll
    for (int j = 0; j < 4; ++j)
        bv[j] = g.bias[n0 + wn * 64 + j * 16 + lm];
#pragma unroll
    for (int i = 0; i < 2; ++i) {
#pragma unroll
        for (int j = 0; j < 4; ++j) {
            int col = n0 + wn * 64 + j * 16 + lm;
#pragma unroll
            for (int r = 0; r < 4; ++r) {
                int row = m0 + wm * 32 + i * 16 + q * 4 + r;
                float v = acc[i][j][r] + bv[j];
                if (g.C16) g.C16[(size_t)row * g.N + col] = f2b(v);
                else       g.Cf[(size_t)row * g.N + col] = v;
            }
        }
    }
}

// ---------------------------------------------------------------------------
// Persistent GRU v4: 64 blocks (1/CU), block owns 16 h-columns.
// w_hh slice (48 x 1024 = 97 KB) in LDS once. h(t) lives in the hsb slice
// (no separate ping-pong buffer). Barrier: exactly ONE agent release fence
// (L2 writeback) + ONE agent acquire fence (L2 inv) per block per step;
// all arrival/poll atomics are RELAXED agent-scope (execute at the
// coherence point, no per-op cache maintenance, poll can't go stale).
// ---------------------------------------------------------------------------
#define GRU_BLOCKS 64
#define WS_STRIDE 1032   // elements; 2064B row stride -> 2-way max bank alias (free)

__device__ __forceinline__ void grid_barrier(int* __restrict__ bar, int t, int bid) {
    __syncthreads();
    if (threadIdx.x == 0) {
        // one L2 writeback: make this block's h/hs writes visible device-wide
        __builtin_amdgcn_fence(__ATOMIC_RELEASE, "agent");
        int g = bid & 7;
        int sub = __hip_atomic_fetch_add(&bar[(t * 8 + g) * 32], 1,
                                         __ATOMIC_RELAXED, __HIP_MEMORY_SCOPE_AGENT);
        if (sub == 7) {
            int m = __hip_atomic_fetch_add(&bar[2560 + t * 32], 1,
                                           __ATOMIC_RELAXED, __HIP_MEMORY_SCOPE_AGENT);
            if (m == 7)
                __hip_atomic_store(&bar[3040], t + 1,
                                   __ATOMIC_RELAXED, __HIP_MEMORY_SCOPE_AGENT);
        }
        while (__hip_atomic_load(&bar[3040], __ATOMIC_RELAXED,
                                 __HIP_MEMORY_SCOPE_AGENT) <= t)
            __builtin_amdgcn_s_sleep(1);
        // one L2 invalidate: drop stale lines before reading others' h
        __builtin_amdgcn_fence(__ATOMIC_ACQUIRE, "agent");
    }
    __syncthreads();
}

__global__ __launch_bounds__(256, 1) void gru_persistent(
    const ushort* __restrict__ w_hhb, const float* __restrict__ bhh,
    const float* __restrict__ GI, const float* __restrict__ hidden,
    const ushort* __restrict__ hb0, ushort* __restrict__ hsb,
    float* __restrict__ outTail, int* __restrict__ bar) {
    __shared__ ushort Ws[48 * WS_STRIDE];   // persistent across steps
    const int tid = threadIdx.x;
    const int w = tid >> 6, lane = tid & 63;
    const int lm = lane & 15, q = lane >> 4;
    const int bid = blockIdx.x;
    const int j0 = bid * 16;
    const int j = j0 + lm;

    // one-time: stage w_hh slice into LDS
#pragma unroll
    for (int p = 0; p < 24; ++p) {
        int c = tid + p * 256;                // 6144 chunks: row=c>>7, off=c&127
        int row = c >> 7, off = c & 127;
        int grow = (row >> 4) * H_DIM + j0 + (row & 15);
        *(short8*)&Ws[row * WS_STRIDE + off * 8] =
            *(const short8*)&w_hhb[(size_t)grow * H_DIM + off * 8];
    }

    const float bhr = bhh[j], bhz = bhh[H_DIM + j], bhn = bhh[2 * H_DIM + j];

    float hf[4];
#pragma unroll
    for (int r = 0; r < 4; ++r)
        hf[r] = hidden[(size_t)(w * 16 + q * 4 + r) * H_DIM + j];

    // GI prefetch for t=0 (in flight across the staging syncthreads)
    float ir[4], iz[4], inn[4];
#pragma unroll
    for (int r = 0; r < 4; ++r) {
        const float* gi = GI + (size_t)(w * 16 + q * 4 + r) * H3 + j;
        ir[r] = gi[0]; iz[r] = gi[H_DIM]; inn[r] = gi[2 * H_DIM];
    }

    __syncthreads();   // Ws ready

    for (int t = 0; t < T_LEN; ++t) {
        const ushort* hin = (t == 0) ? hb0 : hsb + (size_t)(t - 1) * B_SZ * H_DIM;
        ushort* hout = hsb + (size_t)t * B_SZ * H_DIM;
        const ushort* arow = hin + (size_t)(w * 16 + lm) * H_DIM + q * 8;

        // issue all 32 h-chunk loads up front (deep pipeline)
        short8 hreg[32];
#pragma unroll
        for (int c = 0; c < 32; ++c)
            hreg[c] = *(const short8*)&arow[c * 32];

        floatx4 accr = {0.f, 0.f, 0.f, 0.f};
        floatx4 accz = {0.f, 0.f, 0.f, 0.f};
        floatx4 accn = {0.f, 0.f, 0.f, 0.f};

#pragma unroll
        for (int it = 0; it < 8; ++it) {       // K=1024, 128 per iter
#pragma unroll
            for (int kk = 0; kk < 4; ++kk) {
                const short8 af = hreg[it * 4 + kk];
                const int ko = it * 128 + kk * 32 + q * 8;
                short8 b0 = *(const short8*)&Ws[(lm) * WS_STRIDE + ko];
                short8 b1 = *(const short8*)&Ws[(16 + lm) * WS_STRIDE + ko];
                short8 b2 = *(const short8*)&Ws[(32 + lm) * WS_STRIDE + ko];
                accr = __builtin_amdgcn_mfma_f32_16x16x32_bf16(af, b0, accr, 0, 0, 0);
                accz = __builtin_amdgcn_mfma_f32_16x16x32_bf16(af, b1, accz, 0, 0, 0);
                accn = __builtin_amdgcn_mfma_f32_16x16x32_bf16(af, b2, accn, 0, 0, 0);
            }
        }

        // epilogue (ir/iz/inn prefetched before previous barrier)
#pragma unroll
        for (int r = 0; r < 4; ++r) {
            int b = w * 16 + q * 4 + r;
            float rg = fast_sigmoid(ir[r] + accr[r] + bhr);
            float z  = fast_sigmoid(iz[r] + accz[r] + bhz);
            float ng = fast_tanh(inn[r] + rg * (accn[r] + bhn));
            float hnew = (1.f - z) * ng + z * hf[r];
            hf[r] = hnew;
            size_t hi = (size_t)b * H_DIM + j;
            hout[hi] = f2b(hnew);
            if (t == T_LEN - 1) outTail[hi] = hnew;
        }

        if (t < T_LEN - 1) {
            // prefetch GI for t+1 -- lands during the barrier wait
#pragma unroll
            for (int r = 0; r < 4; ++r) {
                const float* gi = GI + (size_t)((t + 1) * B_SZ + w * 16 + q * 4 + r) * H3 + j;
                ir[r] = gi[0]; iz[r] = gi[H_DIM]; inn[r] = gi[2 * H_DIM];
            }
            grid_barrier(bar, t, bid);
        }
    }
}

// ---------------------------------------------------------------------------
// Fused attention: scores + softmax + context + log_softmax.
// ---------------------------------------------------------------------------
__global__ __launch_bounds__(256) void attn_ctx(
    const ushort* __restrict__ WQ16, const ushort* __restrict__ UK16,
    const float* __restrict__ va_w, const float* __restrict__ va_b,
    const ushort* __restrict__ keysb, float* __restrict__ out) {
    __shared__ float wq_s[H_DIM];
    __shared__ float va_s[H_DIM];
    __shared__ float sc[S_LEN];
    __shared__ float wred[4];
    __shared__ float sred[4];
    const int bt = blockIdx.x;       // t*64 + b
    const int t = bt >> 6, b = bt & 63;
    const int tid = threadIdx.x;
    const int wave = tid >> 6, lane = tid & 63;

    for (int hh = tid; hh < H_DIM; hh += 256) {
        wq_s[hh] = b2f(WQ16[(size_t)(t * B_SZ + b) * H_DIM + hh]);
        va_s[hh] = va_w[hh];
    }
    __syncthreads();

    for (int s = wave; s < S_LEN; s += 4) {
        const ushort* uk = UK16 + ((size_t)b * S_LEN + s) * H_DIM + lane * 16;
        short8 u0 = *(const short8*)&uk[0];
        short8 u1 = *(const short8*)&uk[8];
        float acc = 0.f;
        const int h0 = lane * 16;
#pragma unroll
        for (int i = 0; i < 8; ++i)
            acc += fast_tanh(wq_s[h0 + i] + b2f((ushort)u0[i])) * va_s[h0 + i];
#pragma unroll
        for (int i = 0; i < 8; ++i)
            acc += fast_tanh(wq_s[h0 + 8 + i] + b2f((ushort)u1[i])) * va_s[h0 + 8 + i];
        for (int off = 32; off > 0; off >>= 1) acc += __shfl_down(acc, off);
        if (lane == 0) sc[s] = acc + va_b[0];
    }
    __syncthreads();

    if (tid < 64) {
        float v = (tid < S_LEN) ? sc[tid] : -INFINITY;
        float m = v;
        for (int off = 32; off > 0; off >>= 1) m = fmaxf(m, __shfl_down(m, off));
        m = __shfl(m, 0);
        float e = (tid < S_LEN) ? __expf(v - m) : 0.f;
        float sum = e;
        for (int off = 32; off > 0; off >>= 1) sum += __shfl_down(sum, off);
        sum = __shfl(sum, 0);
        if (tid < S_LEN) sc[tid] = e / sum;
    }
    __syncthreads();

    float c[8];
#pragma unroll
    for (int i = 0; i < 8; ++i) c[i] = 0.f;
    const ushort* kb = keysb + (size_t)b * S_LEN * D2H + tid * 8;
    for (int s = 0; s < S_LEN; ++s) {
        float ws = sc[s];
        short8 kv = *(const short8*)&kb[(size_t)s * D2H];
#pragma unroll
        for (int i = 0; i < 8; ++i) c[i] += ws * b2f((ushort)kv[i]);
    }

    float m = c[0];
#pragma unroll
    for (int i = 1; i < 8; ++i) m = fmaxf(m, c[i]);
    for (int off = 32; off > 0; off >>= 1) m = fmaxf(m, __shfl_down(m, off));
    if (lane == 0) wred[wave] = m;
    __syncthreads();
    if (tid == 0) wred[0] = fmaxf(fmaxf(wred[0], wred[1]), fmaxf(wred[2], wred[3]));
    __syncthreads();
    m = wred[0];
    float sum = 0.f;
#pragma unroll
    for (int i = 0; i < 8; ++i) sum += __expf(c[i] - m);
    for (int off = 32; off > 0; off >>= 1) sum += __shfl_down(sum, off);
    if (lane == 0) sred[wave] = sum;
    __syncthreads();
    if (tid == 0) sred[0] = sred[0] + sred[1] + sred[2] + sred[3];
    __syncthreads();
    float lse = m + __logf(sred[0]);

    float* o = out + ((size_t)b * T_LEN + t) * D2H + tid * 8;
#pragma unroll
    for (int i = 0; i < 8; ++i) o[i] = c[i] - lse;
}

// ---------------------------------------------------------------------------
extern "C" void kernel_launch(void* const* d_in, const int* in_sizes, int n_in,
                              void* d_out, int out_size, void* d_ws, size_t ws_size,
                              hipStream_t stream) {
    const float* enc_out = (const float*)d_in[0];
    const float* hidden  = (const float*)d_in[1];
    const int*   target  = (const int*)d_in[2];
    const float* emb     = (const float*)d_in[3];
    const float* w_ih    = (const float*)d_in[4];
    const float* w_hh    = (const float*)d_in[5];
    const float* b_ih    = (const float*)d_in[6];
    const float* b_hh    = (const float*)d_in[7];
    const float* wa_w    = (const float*)d_in[8];
    const float* wa_b    = (const float*)d_in[9];
    const float* ua_w    = (const float*)d_in[10];
    const float* ua_b    = (const float*)d_in[11];
    const float* va_w    = (const float*)d_in[12];
    const float* va_b    = (const float*)d_in[13];
    float* out = (float*)d_out;

    const int TB = T_LEN * B_SZ;               // 640
    const int BS = B_SZ * S_LEN;               // 3200

    // workspace carve
    char* p = (char*)d_ws;
    int*    bar   = (int*)p;    p += 4096 * 4;
    float*  GI    = (float*)p;  p += (size_t)TB * H3 * 4;
    p = (char*)(((uintptr_t)p + 255) & ~(uintptr_t)255);
    ushort* keysb = (ushort*)p; p += (size_t)BS * D2H * 2;
    ushort* Xb    = (ushort*)p; p += (size_t)TB * E_DIM * 2;
    ushort* w_ihb = (ushort*)p; p += (size_t)H3 * E_DIM * 2;
    ushort* w_hhb = (ushort*)p; p += (size_t)H3 * H_DIM * 2;
    ushort* ua_wb = (ushort*)p; p += (size_t)H_DIM * D2H * 2;
    ushort* wa_wb = (ushort*)p; p += (size_t)H_DIM * H_DIM * 2;
    ushort* hb0   = (ushort*)p; p += (size_t)B_SZ * H_DIM * 2;
    ushort* hsb   = (ushort*)p; p += (size_t)TB * H_DIM * 2;
    ushort* UK16  = (ushort*)p; p += (size_t)BS * H_DIM * 2;
    ushort* WQ16  = (ushort*)p; p += (size_t)TB * H_DIM * 2;

    // prep
    prep<<<PB6, 256, 0, stream>>>(w_ih, w_ihb, w_hh, w_hhb, ua_w, ua_wb, wa_w, wa_wb,
                                  enc_out, keysb, target, emb, Xb, hidden, hb0, bar);

    // merged UK + GI GEMMs
    GemmArgs guk = { keysb, ua_wb, ua_b, nullptr, UK16,
                     BS, H_DIM, D2H, H_DIM / 128, (BS / 64) * (H_DIM / 128) };
    GemmArgs ggi = { Xb, w_ihb, b_ih, GI, nullptr,
                     TB, H3, E_DIM, H3 / 128, (TB / 64) * (H3 / 128) };
    gemm_bf16<<<guk.nblk + ggi.nblk, 256, 0, stream>>>(guk, ggi);

    // persistent GRU (h(t) lives in hsb; writes f32 h_last tail)
    float* outTail = out + (size_t)B_SZ * T_LEN * D2H;
    gru_persistent<<<GRU_BLOCKS, 256, 0, stream>>>(w_hhb, b_hh, GI, hidden,
                                                   hb0, hsb, outTail, bar);

    // WQ = hs @ wa_w^T + wa_b  -> bf16
    GemmArgs gwq = { hsb, wa_wb, wa_b, nullptr, WQ16,
                     TB, H_DIM, H_DIM, H_DIM / 128, (TB / 64) * (H_DIM / 128) };
    gemm_bf16<<<gwq.nblk, 256, 0, stream>>>(gwq, gwq);

    // fused attention + context + log_softmax
    attn_ctx<<<B_SZ * T_LEN, 256, 0, stream>>>(WQ16, UK16, va_w, va_b, keysb, out);
}

// Round 8
// 309.166 us; speedup vs baseline: 1.1550x; 1.0768x over previous
//
#include <hip/hip_runtime.h>
#include <math.h>

#define VOCAB 32000
#define E_DIM 512
#define H_DIM 1024
#define S_LEN 50
#define B_SZ 64
#define T_LEN 10
#define H3 (3 * H_DIM)
#define D2H (2 * H_DIM)

typedef __attribute__((ext_vector_type(8))) short short8;
typedef __attribute__((ext_vector_type(4))) float floatx4;

__device__ __forceinline__ ushort f2b(float f) {
    union { float f; uint32_t u; } x; x.f = f;
    uint32_t r = (x.u + 0x7fff + ((x.u >> 16) & 1)) >> 16;  // RNE
    return (ushort)r;
}
__device__ __forceinline__ float b2f(ushort u) {
    union { float f; uint32_t u; } x; x.u = ((uint32_t)u) << 16;
    return x.f;
}
__device__ __forceinline__ float fast_sigmoid(float x) {
    x = fminf(fmaxf(x, -30.f), 30.f);
    return 1.f / (1.f + __expf(-x));
}
__device__ __forceinline__ float fast_tanh(float x) {
    x = fminf(fmaxf(x, -15.f), 15.f);
    float e = __expf(2.f * x);
    return (e - 1.f) / (e + 1.f);
}

// ---------------------------------------------------------------------------
// Fused prep: 4 weight converts + keys gather + embed gather + h0 + barrier init
// ---------------------------------------------------------------------------
#define PB0 1536
#define PB1 (PB0 + 3072)
#define PB2 (PB1 + 2048)
#define PB3 (PB2 + 1024)
#define PB4 (PB3 + 3200)
#define PB5 (PB4 + 640)
#define PB6 (PB5 + 64)

__device__ __forceinline__ void cvt_chunk(const float* src, ushort* dst, int i) {
    float4 v = ((const float4*)src)[i];
    ushort4 o;
    o.x = f2b(v.x); o.y = f2b(v.y); o.z = f2b(v.z); o.w = f2b(v.w);
    ((ushort4*)dst)[i] = o;
}

__global__ __launch_bounds__(256) void prep(
    const float* __restrict__ w_ih, ushort* __restrict__ w_ihb,
    const float* __restrict__ w_hh, ushort* __restrict__ w_hhb,
    const float* __restrict__ ua_w, ushort* __restrict__ ua_wb,
    const float* __restrict__ wa_w, ushort* __restrict__ wa_wb,
    const float* __restrict__ enc_out, ushort* __restrict__ keysb,
    const int* __restrict__ target, const float* __restrict__ emb,
    ushort* __restrict__ Xb,
    const float* __restrict__ hidden, ushort* __restrict__ hb0,
    int* __restrict__ bar) {
    int bid = blockIdx.x, tid = threadIdx.x;
    if (bid == 0) {
        for (int i = tid; i < 4096; i += 256)
            __hip_atomic_store(&bar[i], 0, __ATOMIC_RELAXED, __HIP_MEMORY_SCOPE_SYSTEM);
    }
    if (bid < PB0) {
        cvt_chunk(w_ih, w_ihb, bid * 256 + tid);
    } else if (bid < PB1) {
        cvt_chunk(w_hh, w_hhb, (bid - PB0) * 256 + tid);
    } else if (bid < PB2) {
        cvt_chunk(ua_w, ua_wb, (bid - PB1) * 256 + tid);
    } else if (bid < PB3) {
        cvt_chunk(wa_w, wa_wb, (bid - PB2) * 256 + tid);
    } else if (bid < PB4) {
        int bs = bid - PB3;                   // b*S + s
        int b = bs / S_LEN, s = bs % S_LEN;
        const float* src = enc_out + ((size_t)s * B_SZ + b) * D2H;
        ushort* dst = keysb + (size_t)bs * D2H;
#pragma unroll
        for (int p = 0; p < 2; ++p) {
            int i = tid + p * 256;
            float4 v = ((const float4*)src)[i];
            ushort4 o;
            o.x = f2b(v.x); o.y = f2b(v.y); o.z = f2b(v.z); o.w = f2b(v.w);
            ((ushort4*)dst)[i] = o;
        }
    } else if (bid < PB5) {
        int m = bid - PB4;                    // t*B + b
        int t = m / B_SZ, b = m % B_SZ;
        int idx = (t == 0) ? 0 : target[b * T_LEN + (t - 1)];
        if (tid < 128) {
            const float* src = emb + (size_t)idx * E_DIM;
            float4 v = ((const float4*)src)[tid];
            ushort4 o;
            o.x = f2b(v.x); o.y = f2b(v.y); o.z = f2b(v.z); o.w = f2b(v.w);
            ((ushort4*)(Xb + (size_t)m * E_DIM))[tid] = o;
        }
    } else {
        cvt_chunk(hidden, hb0, (bid - PB5) * 256 + tid);
    }
}

// ---------------------------------------------------------------------------
// bf16 MFMA GEMM: C = A[M,K] @ W[N,K]^T + bias. BM=64, BN=128, BK=64.
// Two GEMMs merged per dispatch via GemmArgs pair (bid switch).
// ---------------------------------------------------------------------------
struct GemmArgs {
    const ushort* A; const ushort* W; const float* bias;
    float* Cf; ushort* C16;
    int M, N, K, nbn, nblk;
};

__global__ __launch_bounds__(256) void gemm_bf16(GemmArgs g0, GemmArgs g1) {
    const bool first = (int)blockIdx.x < g0.nblk;
    GemmArgs g = first ? g0 : g1;
    const int bid = first ? blockIdx.x : (blockIdx.x - g0.nblk);

    __shared__ ushort As[64 * 72];
    __shared__ ushort Bs[128 * 72];

    const int tid = threadIdx.x;
    const int w = tid >> 6, lane = tid & 63;
    const int lm = lane & 15, q = lane >> 4;
    const int wm = w >> 1, wn = w & 1;
    const int n0 = (bid % g.nbn) * 128;
    const int m0 = (bid / g.nbn) * 64;
    const int K = g.K;

    floatx4 acc[2][4];
#pragma unroll
    for (int i = 0; i < 2; ++i)
#pragma unroll
        for (int j = 0; j < 4; ++j)
            acc[i][j] = (floatx4){0.f, 0.f, 0.f, 0.f};

    short8 ar[2], br[4];
    auto load_tiles = [&](int k0) {
#pragma unroll
        for (int p = 0; p < 2; ++p) {
            int c = tid + p * 256;
            ar[p] = *(const short8*)&g.A[(size_t)(m0 + (c >> 3)) * K + k0 + (c & 7) * 8];
        }
#pragma unroll
        for (int p = 0; p < 4; ++p) {
            int c = tid + p * 256;
            br[p] = *(const short8*)&g.W[(size_t)(n0 + (c >> 3)) * K + k0 + (c & 7) * 8];
        }
    };

    load_tiles(0);
    for (int k0 = 0; k0 < K; k0 += 64) {
#pragma unroll
        for (int p = 0; p < 2; ++p) {
            int c = tid + p * 256;
            *(short8*)&As[(c >> 3) * 72 + (c & 7) * 8] = ar[p];
        }
#pragma unroll
        for (int p = 0; p < 4; ++p) {
            int c = tid + p * 256;
            *(short8*)&Bs[(c >> 3) * 72 + (c & 7) * 8] = br[p];
        }
        __syncthreads();
        if (k0 + 64 < K) load_tiles(k0 + 64);

#pragma unroll
        for (int kk = 0; kk < 2; ++kk) {
            short8 af[2], bf[4];
#pragma unroll
            for (int i = 0; i < 2; ++i)
                af[i] = *(const short8*)&As[(wm * 32 + i * 16 + lm) * 72 + kk * 32 + q * 8];
#pragma unroll
            for (int j = 0; j < 4; ++j)
                bf[j] = *(const short8*)&Bs[(wn * 64 + j * 16 + lm) * 72 + kk * 32 + q * 8];
#pragma unroll
            for (int i = 0; i < 2; ++i)
#pragma unroll
                for (int j = 0; j < 4; ++j)
                    acc[i][j] = __builtin_amdgcn_mfma_f32_16x16x32_bf16(af[i], bf[j], acc[i][j], 0, 0, 0);
        }
        __syncthreads();
    }

    float bv[4];
#pragma unroll
    for (int j = 0; j < 4; ++j)
        bv[j] = g.bias[n0 + wn * 64 + j * 16 + lm];
#pragma unroll
    for (int i = 0; i < 2; ++i) {
#pragma unroll
        for (int j = 0; j < 4; ++j) {
            int col = n0 + wn * 64 + j * 16 + lm;
#pragma unroll
            for (int r = 0; r < 4; ++r) {
                int row = m0 + wm * 32 + i * 16 + q * 4 + r;
                float v = acc[i][j][r] + bv[j];
                if (g.C16) g.C16[(size_t)row * g.N + col] = f2b(v);
                else       g.Cf[(size_t)row * g.N + col] = v;
            }
        }
    }
}

// ---------------------------------------------------------------------------
// Persistent GRU v5: 64 blocks (1/CU), block owns 16 h-columns.
// w_hh slice (97 KB) in LDS once. h moves through the COHERENCE POINT only:
// stores = system-scope relaxed atomic uint (sc0 sc1 write-through),
// loads = inline-asm global_load_dwordx4 sc0 sc1 (bypass stale L2), all 32
// issued back-to-back with ONE waitcnt. NO cache-maintenance fences at all.
// Barrier: relaxed hierarchical arrival + relaxed poll.
// ---------------------------------------------------------------------------
#define GRU_BLOCKS 64
#define WS_STRIDE 1032   // elements; 2064B row stride -> 2-way max bank alias (free)

__device__ __forceinline__ void grid_barrier(int* __restrict__ bar, int t, int bid) {
    __syncthreads();   // pre-barrier waitcnt drains this wave's write-through stores
    if (threadIdx.x == 0) {
        int g = bid & 7;
        int sub = __hip_atomic_fetch_add(&bar[(t * 8 + g) * 32], 1,
                                         __ATOMIC_RELAXED, __HIP_MEMORY_SCOPE_SYSTEM);
        if (sub == 7) {
            int m = __hip_atomic_fetch_add(&bar[2560 + t * 32], 1,
                                           __ATOMIC_RELAXED, __HIP_MEMORY_SCOPE_SYSTEM);
            if (m == 7)
                __hip_atomic_store(&bar[3040], t + 1,
                                   __ATOMIC_RELAXED, __HIP_MEMORY_SCOPE_SYSTEM);
        }
        while (__hip_atomic_load(&bar[3040], __ATOMIC_RELAXED,
                                 __HIP_MEMORY_SCOPE_SYSTEM) <= t)
            __builtin_amdgcn_s_sleep(1);
    }
    __syncthreads();
}

__global__ __launch_bounds__(256, 1) void gru_persistent(
    const ushort* __restrict__ w_hhb, const float* __restrict__ bhh,
    const float* __restrict__ GI, const float* __restrict__ hidden,
    const ushort* __restrict__ hb0, ushort* __restrict__ hsb,
    float* __restrict__ outTail, int* __restrict__ bar) {
    __shared__ ushort Ws[48 * WS_STRIDE];   // persistent across steps
    const int tid = threadIdx.x;
    const int w = tid >> 6, lane = tid & 63;
    const int lm = lane & 15, q = lane >> 4;
    const int bid = blockIdx.x;
    const int j0 = bid * 16;
    const int j = j0 + lm;

    // one-time: stage w_hh slice into LDS
#pragma unroll
    for (int p = 0; p < 24; ++p) {
        int c = tid + p * 256;                // 6144 chunks: row=c>>7, off=c&127
        int row = c >> 7, off = c & 127;
        int grow = (row >> 4) * H_DIM + j0 + (row & 15);
        *(short8*)&Ws[row * WS_STRIDE + off * 8] =
            *(const short8*)&w_hhb[(size_t)grow * H_DIM + off * 8];
    }

    const float bhr = bhh[j], bhz = bhh[H_DIM + j], bhn = bhh[2 * H_DIM + j];

    float hf[4];
#pragma unroll
    for (int r = 0; r < 4; ++r)
        hf[r] = hidden[(size_t)(w * 16 + q * 4 + r) * H_DIM + j];

    // GI prefetch for t=0
    float ir[4], iz[4], inn[4];
#pragma unroll
    for (int r = 0; r < 4; ++r) {
        const float* gi = GI + (size_t)(w * 16 + q * 4 + r) * H3 + j;
        ir[r] = gi[0]; iz[r] = gi[H_DIM]; inn[r] = gi[2 * H_DIM];
    }

    __syncthreads();   // Ws ready

    for (int t = 0; t < T_LEN; ++t) {
        const ushort* hin = (t == 0) ? hb0 : hsb + (size_t)(t - 1) * B_SZ * H_DIM;
        ushort* hout = hsb + (size_t)t * B_SZ * H_DIM;
        const ushort* arow = hin + (size_t)(w * 16 + lm) * H_DIM + q * 8;

        // all 32 h-chunk loads, coherence-point reads, one waitcnt
        short8 hr[32];
        asm volatile(
            "global_load_dwordx4 %[h0], %[a], off sc0 sc1\n\t"
            "global_load_dwordx4 %[h1], %[a], off offset:64 sc0 sc1\n\t"
            "global_load_dwordx4 %[h2], %[a], off offset:128 sc0 sc1\n\t"
            "global_load_dwordx4 %[h3], %[a], off offset:192 sc0 sc1\n\t"
            "global_load_dwordx4 %[h4], %[a], off offset:256 sc0 sc1\n\t"
            "global_load_dwordx4 %[h5], %[a], off offset:320 sc0 sc1\n\t"
            "global_load_dwordx4 %[h6], %[a], off offset:384 sc0 sc1\n\t"
            "global_load_dwordx4 %[h7], %[a], off offset:448 sc0 sc1\n\t"
            "global_load_dwordx4 %[h8], %[a], off offset:512 sc0 sc1\n\t"
            "global_load_dwordx4 %[h9], %[a], off offset:576 sc0 sc1\n\t"
            "global_load_dwordx4 %[h10], %[a], off offset:640 sc0 sc1\n\t"
            "global_load_dwordx4 %[h11], %[a], off offset:704 sc0 sc1\n\t"
            "global_load_dwordx4 %[h12], %[a], off offset:768 sc0 sc1\n\t"
            "global_load_dwordx4 %[h13], %[a], off offset:832 sc0 sc1\n\t"
            "global_load_dwordx4 %[h14], %[a], off offset:896 sc0 sc1\n\t"
            "global_load_dwordx4 %[h15], %[a], off offset:960 sc0 sc1\n\t"
            "global_load_dwordx4 %[h16], %[a], off offset:1024 sc0 sc1\n\t"
            "global_load_dwordx4 %[h17], %[a], off offset:1088 sc0 sc1\n\t"
            "global_load_dwordx4 %[h18], %[a], off offset:1152 sc0 sc1\n\t"
            "global_load_dwordx4 %[h19], %[a], off offset:1216 sc0 sc1\n\t"
            "global_load_dwordx4 %[h20], %[a], off offset:1280 sc0 sc1\n\t"
            "global_load_dwordx4 %[h21], %[a], off offset:1344 sc0 sc1\n\t"
            "global_load_dwordx4 %[h22], %[a], off offset:1408 sc0 sc1\n\t"
            "global_load_dwordx4 %[h23], %[a], off offset:1472 sc0 sc1\n\t"
            "global_load_dwordx4 %[h24], %[a], off offset:1536 sc0 sc1\n\t"
            "global_load_dwordx4 %[h25], %[a], off offset:1600 sc0 sc1\n\t"
            "global_load_dwordx4 %[h26], %[a], off offset:1664 sc0 sc1\n\t"
            "global_load_dwordx4 %[h27], %[a], off offset:1728 sc0 sc1\n\t"
            "global_load_dwordx4 %[h28], %[a], off offset:1792 sc0 sc1\n\t"
            "global_load_dwordx4 %[h29], %[a], off offset:1856 sc0 sc1\n\t"
            "global_load_dwordx4 %[h30], %[a], off offset:1920 sc0 sc1\n\t"
            "global_load_dwordx4 %[h31], %[a], off offset:1984 sc0 sc1\n\t"
            "s_waitcnt vmcnt(0)"
            : [h0] "=&v"(hr[0]), [h1] "=&v"(hr[1]), [h2] "=&v"(hr[2]), [h3] "=&v"(hr[3]),
              [h4] "=&v"(hr[4]), [h5] "=&v"(hr[5]), [h6] "=&v"(hr[6]), [h7] "=&v"(hr[7]),
              [h8] "=&v"(hr[8]), [h9] "=&v"(hr[9]), [h10] "=&v"(hr[10]), [h11] "=&v"(hr[11]),
              [h12] "=&v"(hr[12]), [h13] "=&v"(hr[13]), [h14] "=&v"(hr[14]), [h15] "=&v"(hr[15]),
              [h16] "=&v"(hr[16]), [h17] "=&v"(hr[17]), [h18] "=&v"(hr[18]), [h19] "=&v"(hr[19]),
              [h20] "=&v"(hr[20]), [h21] "=&v"(hr[21]), [h22] "=&v"(hr[22]), [h23] "=&v"(hr[23]),
              [h24] "=&v"(hr[24]), [h25] "=&v"(hr[25]), [h26] "=&v"(hr[26]), [h27] "=&v"(hr[27]),
              [h28] "=&v"(hr[28]), [h29] "=&v"(hr[29]), [h30] "=&v"(hr[30]), [h31] "=&v"(hr[31])
            : [a] "v"(arow)
            : "memory");

        floatx4 accr = {0.f, 0.f, 0.f, 0.f};
        floatx4 accz = {0.f, 0.f, 0.f, 0.f};
        floatx4 accn = {0.f, 0.f, 0.f, 0.f};

#pragma unroll
        for (int it = 0; it < 8; ++it) {       // K=1024, 128 per iter
#pragma unroll
            for (int kk = 0; kk < 4; ++kk) {
                const short8 af = hr[it * 4 + kk];
                const int ko = it * 128 + kk * 32 + q * 8;
                short8 b0 = *(const short8*)&Ws[(lm) * WS_STRIDE + ko];
                short8 b1 = *(const short8*)&Ws[(16 + lm) * WS_STRIDE + ko];
                short8 b2 = *(const short8*)&Ws[(32 + lm) * WS_STRIDE + ko];
                accr = __builtin_amdgcn_mfma_f32_16x16x32_bf16(af, b0, accr, 0, 0, 0);
                accz = __builtin_amdgcn_mfma_f32_16x16x32_bf16(af, b1, accz, 0, 0, 0);
                accn = __builtin_amdgcn_mfma_f32_16x16x32_bf16(af, b2, accn, 0, 0, 0);
            }
        }

        // epilogue: compute h_new, store via write-through packed uints
        int h16v[4];
#pragma unroll
        for (int r = 0; r < 4; ++r) {
            float rg = fast_sigmoid(ir[r] + accr[r] + bhr);
            float z  = fast_sigmoid(iz[r] + accz[r] + bhz);
            float ng = fast_tanh(inn[r] + rg * (accn[r] + bhn));
            float hnew = (1.f - z) * ng + z * hf[r];
            hf[r] = hnew;
            h16v[r] = (int)f2b(hnew);
            if (t == T_LEN - 1) {
                int b = w * 16 + q * 4 + r;
                outTail[(size_t)b * H_DIM + j] = hnew;
            }
        }
#pragma unroll
        for (int r = 0; r < 4; ++r) {
            int pv = __shfl(h16v[r], (lane + 1) & 63);   // partner lane's column j+1
            if ((lm & 1) == 0) {
                int b = w * 16 + q * 4 + r;
                uint packed = (uint)(h16v[r] & 0xffff) | ((uint)pv << 16);
                __hip_atomic_store((uint*)hout + ((size_t)b * H_DIM + j) / 2, packed,
                                   __ATOMIC_RELAXED, __HIP_MEMORY_SCOPE_SYSTEM);
            }
        }

        if (t < T_LEN - 1) {
            // prefetch GI for t+1 (L2-resident now; lands during barrier wait)
#pragma unroll
            for (int r = 0; r < 4; ++r) {
                const float* gi = GI + (size_t)((t + 1) * B_SZ + w * 16 + q * 4 + r) * H3 + j;
                ir[r] = gi[0]; iz[r] = gi[H_DIM]; inn[r] = gi[2 * H_DIM];
            }
            grid_barrier(bar, t, bid);
        }
    }
}

// ---------------------------------------------------------------------------
// Fused attention: scores + softmax + context + log_softmax.
// ---------------------------------------------------------------------------
__global__ __launch_bounds__(256) void attn_ctx(
    const ushort* __restrict__ WQ16, const ushort* __restrict__ UK16,
    const float* __restrict__ va_w, const float* __restrict__ va_b,
    const ushort* __restrict__ keysb, float* __restrict__ out) {
    __shared__ float wq_s[H_DIM];
    __shared__ float va_s[H_DIM];
    __shared__ float sc[S_LEN];
    __shared__ float wred[4];
    __shared__ float sred[4];
    const int bt = blockIdx.x;       // t*64 + b
    const int t = bt >> 6, b = bt & 63;
    const int tid = threadIdx.x;
    const int wave = tid >> 6, lane = tid & 63;

    for (int hh = tid; hh < H_DIM; hh += 256) {
        wq_s[hh] = b2f(WQ16[(size_t)(t * B_SZ + b) * H_DIM + hh]);
        va_s[hh] = va_w[hh];
    }
    __syncthreads();

    for (int s = wave; s < S_LEN; s += 4) {
        const ushort* uk = UK16 + ((size_t)b * S_LEN + s) * H_DIM + lane * 16;
        short8 u0 = *(const short8*)&uk[0];
        short8 u1 = *(const short8*)&uk[8];
        float acc = 0.f;
        const int h0 = lane * 16;
#pragma unroll
        for (int i = 0; i < 8; ++i)
            acc += fast_tanh(wq_s[h0 + i] + b2f((ushort)u0[i])) * va_s[h0 + i];
#pragma unroll
        for (int i = 0; i < 8; ++i)
            acc += fast_tanh(wq_s[h0 + 8 + i] + b2f((ushort)u1[i])) * va_s[h0 + 8 + i];
        for (int off = 32; off > 0; off >>= 1) acc += __shfl_down(acc, off);
        if (lane == 0) sc[s] = acc + va_b[0];
    }
    __syncthreads();

    if (tid < 64) {
        float v = (tid < S_LEN) ? sc[tid] : -INFINITY;
        float m = v;
        for (int off = 32; off > 0; off >>= 1) m = fmaxf(m, __shfl_down(m, off));
        m = __shfl(m, 0);
        float e = (tid < S_LEN) ? __expf(v - m) : 0.f;
        float sum = e;
        for (int off = 32; off > 0; off >>= 1) sum += __shfl_down(sum, off);
        sum = __shfl(sum, 0);
        if (tid < S_LEN) sc[tid] = e / sum;
    }
    __syncthreads();

    float c[8];
#pragma unroll
    for (int i = 0; i < 8; ++i) c[i] = 0.f;
    const ushort* kb = keysb + (size_t)b * S_LEN * D2H + tid * 8;
    for (int s = 0; s < S_LEN; ++s) {
        float ws = sc[s];
        short8 kv = *(const short8*)&kb[(size_t)s * D2H];
#pragma unroll
        for (int i = 0; i < 8; ++i) c[i] += ws * b2f((ushort)kv[i]);
    }

    float m = c[0];
#pragma unroll
    for (int i = 1; i < 8; ++i) m = fmaxf(m, c[i]);
    for (int off = 32; off > 0; off >>= 1) m = fmaxf(m, __shfl_down(m, off));
    if (lane == 0) wred[wave] = m;
    __syncthreads();
    if (tid == 0) wred[0] = fmaxf(fmaxf(wred[0], wred[1]), fmaxf(wred[2], wred[3]));
    __syncthreads();
    m = wred[0];
    float sum = 0.f;
#pragma unroll
    for (int i = 0; i < 8; ++i) sum += __expf(c[i] - m);
    for (int off = 32; off > 0; off >>= 1) sum += __shfl_down(sum, off);
    if (lane == 0) sred[wave] = sum;
    __syncthreads();
    if (tid == 0) sred[0] = sred[0] + sred[1] + sred[2] + sred[3];
    __syncthreads();
    float lse = m + __logf(sred[0]);

    float* o = out + ((size_t)b * T_LEN + t) * D2H + tid * 8;
#pragma unroll
    for (int i = 0; i < 8; ++i) o[i] = c[i] - lse;
}

// ---------------------------------------------------------------------------
extern "C" void kernel_launch(void* const* d_in, const int* in_sizes, int n_in,
                              void* d_out, int out_size, void* d_ws, size_t ws_size,
                              hipStream_t stream) {
    const float* enc_out = (const float*)d_in[0];
    const float* hidden  = (const float*)d_in[1];
    const int*   target  = (const int*)d_in[2];
    const float* emb     = (const float*)d_in[3];
    const float* w_ih    = (const float*)d_in[4];
    const float* w_hh    = (const float*)d_in[5];
    const float* b_ih    = (const float*)d_in[6];
    const float* b_hh    = (const float*)d_in[7];
    const float* wa_w    = (const float*)d_in[8];
    const float* wa_b    = (const float*)d_in[9];
    const float* ua_w    = (const float*)d_in[10];
    const float* ua_b    = (const float*)d_in[11];
    const float* va_w    = (const float*)d_in[12];
    const float* va_b    = (const float*)d_in[13];
    float* out = (float*)d_out;

    const int TB = T_LEN * B_SZ;               // 640
    const int BS = B_SZ * S_LEN;               // 3200

    // workspace carve
    char* p = (char*)d_ws;
    int*    bar   = (int*)p;    p += 4096 * 4;
    float*  GI    = (float*)p;  p += (size_t)TB * H3 * 4;
    p = (char*)(((uintptr_t)p + 255) & ~(uintptr_t)255);
    ushort* keysb = (ushort*)p; p += (size_t)BS * D2H * 2;
    ushort* Xb    = (ushort*)p; p += (size_t)TB * E_DIM * 2;
    ushort* w_ihb = (ushort*)p; p += (size_t)H3 * E_DIM * 2;
    ushort* w_hhb = (ushort*)p; p += (size_t)H3 * H_DIM * 2;
    ushort* ua_wb = (ushort*)p; p += (size_t)H_DIM * D2H * 2;
    ushort* wa_wb = (ushort*)p; p += (size_t)H_DIM * H_DIM * 2;
    ushort* hb0   = (ushort*)p; p += (size_t)B_SZ * H_DIM * 2;
    ushort* hsb   = (ushort*)p; p += (size_t)TB * H_DIM * 2;
    ushort* UK16  = (ushort*)p; p += (size_t)BS * H_DIM * 2;
    ushort* WQ16  = (ushort*)p; p += (size_t)TB * H_DIM * 2;

    // prep
    prep<<<PB6, 256, 0, stream>>>(w_ih, w_ihb, w_hh, w_hhb, ua_w, ua_wb, wa_w, wa_wb,
                                  enc_out, keysb, target, emb, Xb, hidden, hb0, bar);

    // merged UK + GI GEMMs
    GemmArgs guk = { keysb, ua_wb, ua_b, nullptr, UK16,
                     BS, H_DIM, D2H, H_DIM / 128, (BS / 64) * (H_DIM / 128) };
    GemmArgs ggi = { Xb, w_ihb, b_ih, GI, nullptr,
                     TB, H3, E_DIM, H3 / 128, (TB / 64) * (H3 / 128) };
    gemm_bf16<<<guk.nblk + ggi.nblk, 256, 0, stream>>>(guk, ggi);

    // persistent GRU (h(t) lives in hsb; writes f32 h_last tail)
    float* outTail = out + (size_t)B_SZ * T_LEN * D2H;
    gru_persistent<<<GRU_BLOCKS, 256, 0, stream>>>(w_hhb, b_hh, GI, hidden,
                                                   hb0, hsb, outTail, bar);

    // WQ = hs @ wa_w^T + wa_b  -> bf16
    GemmArgs gwq = { hsb, wa_wb, wa_b, nullptr, WQ16,
                     TB, H_DIM, H_DIM, H_DIM / 128, (TB / 64) * (H_DIM / 128) };
    gemm_bf16<<<gwq.nblk, 256, 0, stream>>>(gwq, gwq);

    // fused attention + context + log_softmax
    attn_ctx<<<B_SZ * T_LEN, 256, 0, stream>>>(WQ16, UK16, va_w, va_b, keysb, out);
}